// Round 9
// baseline (188.773 us; speedup 1.0000x reference)
//
#include <hip/hip_runtime.h>
#include <hip/hip_bf16.h>

// n=8192 rows, d=256 feat, 10 classes.
// loss = mean_i log1p(exp(0.5/0.7) * A_i * B_i)
//   A_i = sum_{j: y_j!=y_i} exp(sim_ij/0.7), B_i = sum_{j!=i: y_j==y_i} exp(-sim_ij/0.7)
//   sim = rownorm(P) @ rownorm(P)^T  (symmetric)
//
// R9: R8 exactly, minus ALL global atomics in k_main (single-variable test of
// the atomic-coherence theory for R8's 92/98 MB HBM traffic). Row-credit and
// col-credit partials go to block-exclusive ws slots via plain coalesced
// stores; k_final (32 blocks) gathers each row's writer slots (triangular
// index arithmetic), builds hist per-block via ballot, atomic-merges 32 block
// sums into memset-zeroed out[0].
//
// ws layout (ASSUMES ws_size >= ~7.3 MB; 4.25 MB proven in R1-R8):
//   Pn      bf16 [8192*256]                @ 0        (4,194,304 B)
//   rowPart float2 [1056 blocks * 128 row] @ 4 MB     (1,081,344 B)
//   colPart float2 [1056 blocks * 256 col] @ ~5.08 MB (2,162,688 B)

#define NF 256
#define TINV (1.0f / 0.7f)
#define SC2 2.0609929398439434f  // (1/0.7)*log2(e)

typedef __attribute__((ext_vector_type(8))) short short8;
typedef __attribute__((ext_vector_type(4))) float float4v;

typedef const __attribute__((address_space(1))) unsigned int glb_u32;
typedef __attribute__((address_space(3))) unsigned int lds_u32;

// One wave per row: normalize to bf16.
__global__ __launch_bounds__(256)
void k_prep(const float* __restrict__ P, unsigned short* __restrict__ Pn) {
    int wave = threadIdx.x >> 6, lane = threadIdx.x & 63;
    int row = blockIdx.x * 4 + wave;
    float4 v = *(const float4*)(P + (size_t)row * NF + lane * 4);
    float sq = v.x * v.x + v.y * v.y + v.z * v.z + v.w * v.w;
#pragma unroll
    for (int off = 32; off; off >>= 1) sq += __shfl_xor(sq, off, 64);
    float r = rsqrtf(sq);
    __hip_bfloat16 h0 = __float2bfloat16(v.x * r), h1 = __float2bfloat16(v.y * r),
                   h2 = __float2bfloat16(v.z * r), h3 = __float2bfloat16(v.w * r);
    ushort4 o = { *(unsigned short*)&h0, *(unsigned short*)&h1,
                  *(unsigned short*)&h2, *(unsigned short*)&h3 };
    *(ushort4*)(Pn + (size_t)row * NF + lane * 4) = o;
}

__global__ __launch_bounds__(256, 3)
void k_main(const unsigned short* __restrict__ Pn, const int* __restrict__ y,
            float2* __restrict__ rowPart, float2* __restrict__ colPart) {
    __shared__ __align__(16) unsigned short Bs[64 * NF];  // one 64-col chunk
    __shared__ int yc[256];
    __shared__ float colA[256], colB[256];

    // Triangular decode: starts s(2a)=a^2+a, s(2a+1)=(a+1)^2.
    const int bid = blockIdx.x;
    int a0 = (int)sqrtf((float)bid + 0.25f);
    while (a0 * a0 + a0 > bid) --a0;
    while ((a0 + 1) * (a0 + 1) + (a0 + 1) <= bid) ++a0;
    int I, J;
    const int so = (a0 + 1) * (a0 + 1);
    if (bid < so) { I = 2 * a0;     J = bid - (a0 * a0 + a0); }
    else          { I = 2 * a0 + 1; J = bid - so; }
    const int rb = I * 128, cb0 = J * 256;
    const int nc = min(4, (rb + 128 - cb0 + 63) >> 6);  // valid 64-col chunks

    const int tid = threadIdx.x;
    yc[tid] = y[cb0 + tid];
    colA[tid] = 0.f; colB[tid] = 0.f;

    const int lane = tid & 63, wave = tid >> 6;
    const int quad = lane >> 4, l15 = lane & 15;

    // A-frags: wave's 32 rows x full K. m=l15, k=quad*8+j (16x16x32).
    const unsigned short* pa = Pn + (size_t)(rb + wave * 32 + l15) * NF + quad * 8;
    short8 afr[2][8];
#pragma unroll
    for (int tr = 0; tr < 2; ++tr)
#pragma unroll
        for (int ks = 0; ks < 8; ++ks)
            afr[tr][ks] = *(const short8*)(pa + (size_t)tr * 16 * NF + ks * 32);

    // Row classes byte-packed (rows tr*16 + quad*4 + r).
    unsigned yis[2];
#pragma unroll
    for (int tr = 0; tr < 2; ++tr) {
        int4 v = *(const int4*)(y + rb + wave * 32 + tr * 16 + quad * 4);
        yis[tr] = (unsigned)(v.x & 255) | ((unsigned)(v.y & 255) << 8) |
                  ((unsigned)(v.z & 255) << 16) | ((unsigned)(v.w & 255) << 24);
    }

    float rA[2][4], rB[2][4];
#pragma unroll
    for (int tr = 0; tr < 2; ++tr)
#pragma unroll
        for (int r = 0; r < 4; ++r) { rA[tr][r] = 0.f; rB[tr][r] = 0.f; }

    // DMA one 64-col chunk (kc-major: ushort addr = kc*512 + col*8).
#define DMA_CHUNK(c)                                                          \
    {                                                                         \
        _Pragma("unroll")                                                     \
        for (int i = 0; i < 8; ++i) {                                         \
            const int kc = wave * 8 + i;                                      \
            const unsigned short* src =                                       \
                Pn + (size_t)(cb0 + (c) * 64 + lane) * NF + kc * 8;           \
            __builtin_amdgcn_global_load_lds((glb_u32*)src,                   \
                (lds_u32*)&Bs[kc * 512], 16, 0, 0);                           \
        }                                                                     \
    }

    DMA_CHUNK(0)

#pragma unroll 1
    for (int c = 0; c < nc; ++c) {
        __syncthreads();   // barrier drains DMA vmcnt -> Bs ready

        float4v acc[2][4];
#pragma unroll
        for (int a = 0; a < 2; ++a)
#pragma unroll
            for (int b = 0; b < 4; ++b) acc[a][b] = (float4v){0.f, 0.f, 0.f, 0.f};

#pragma unroll
        for (int ks = 0; ks < 8; ++ks) {
            short8 fb[4];
#pragma unroll
            for (int tc = 0; tc < 4; ++tc)
                fb[tc] = *(const short8*)&Bs[(ks * 4 + quad) * 512 + (tc * 16 + l15) * 8];
#pragma unroll
            for (int tr = 0; tr < 2; ++tr)
#pragma unroll
                for (int tc = 0; tc < 4; ++tc)
                    acc[tr][tc] = __builtin_amdgcn_mfma_f32_16x16x32_bf16(
                        afr[tr][ks], fb[tc], acc[tr][tc], 0, 0, 0);
        }
        __syncthreads();   // all waves done reading Bs
        if (c + 1 < nc) DMA_CHUNK(c + 1)

        // Fused epilogue. C/D: col=l15, row=quad*4+reg. Mask j<i.
        float cA[4] = {0.f, 0.f, 0.f, 0.f}, cB[4] = {0.f, 0.f, 0.f, 0.f};
#pragma unroll
        for (int tc = 0; tc < 4; ++tc) {
            const int jl = c * 64 + tc * 16 + l15;
            const int yj = yc[jl];
            const int gj = cb0 + jl;
#pragma unroll
            for (int tr = 0; tr < 2; ++tr) {
                const int gi0 = rb + wave * 32 + tr * 16 + quad * 4;
#pragma unroll
                for (int r = 0; r < 4; ++r) {
                    const float s = acc[tr][tc][r];
                    const int cls = (yis[tr] >> (8 * r)) & 255;
                    const bool same = (cls == yj);
                    const bool valid = (gj < gi0 + r);   // strict lower triangle
                    const float e = exp2f(s * (same ? -SC2 : SC2));
                    const float ea = (valid && !same) ? e : 0.f;
                    const float eb = (valid && same) ? e : 0.f;
                    rA[tr][r] += ea; rB[tr][r] += eb;
                    cA[tc] += ea;    cB[tc] += eb;
                }
            }
        }
        // Col-credit: reduce over quads, LDS-accumulate (sim_ji == sim_ij).
#pragma unroll
        for (int tc = 0; tc < 4; ++tc) {
            cA[tc] += __shfl_xor(cA[tc], 16, 64);
            cA[tc] += __shfl_xor(cA[tc], 32, 64);
            cB[tc] += __shfl_xor(cB[tc], 16, 64);
            cB[tc] += __shfl_xor(cB[tc], 32, 64);
        }
        if (quad == 0) {
#pragma unroll
            for (int tc = 0; tc < 4; ++tc) {
                atomicAdd(&colA[c * 64 + tc * 16 + l15], cA[tc]);   // LDS, CU-local
                atomicAdd(&colB[c * 64 + tc * 16 + l15], cB[tc]);
            }
        }
    }

    // Row-credit: butterfly over 16 col-lanes; quad leaders STORE partials.
#pragma unroll
    for (int tr = 0; tr < 2; ++tr)
#pragma unroll
        for (int r = 0; r < 4; ++r) {
#pragma unroll
            for (int off = 1; off < 16; off <<= 1) {
                rA[tr][r] += __shfl_xor(rA[tr][r], off, 64);
                rB[tr][r] += __shfl_xor(rB[tr][r], off, 64);
            }
        }
    if (l15 == 0) {
#pragma unroll
        for (int tr = 0; tr < 2; ++tr)
#pragma unroll
            for (int r = 0; r < 4; ++r) {
                const int lr = wave * 32 + tr * 16 + quad * 4 + r;
                rowPart[(size_t)bid * 128 + lr] = make_float2(rA[tr][r], rB[tr][r]);
            }
    }

    // Col-credit flush: plain stores, all 256 slots (beyond nc*64 are zeros).
    __syncthreads();
    colPart[(size_t)bid * 256 + tid] = make_float2(colA[tid], colB[tid]);
}

// 32 blocks x 256: gather each row's writer slots, hist via ballot,
// atomic-merge block sums into memset-zeroed out[0].
__global__ __launch_bounds__(256)
void k_final(const float2* __restrict__ rowPart, const float2* __restrict__ colPart,
             const int* __restrict__ y, float* __restrict__ out, int n) {
    __shared__ int hist[16];
    __shared__ float red[4];
    const int tid = threadIdx.x;
    const int r = blockIdx.x * 256 + tid;

    if (tid < 16) hist[tid] = 0;
    __syncthreads();
    {
        int loc[10];
#pragma unroll
        for (int cc = 0; cc < 10; ++cc) loc[cc] = 0;
        for (int i = tid; i < n; i += 256) {
            const int yv = y[i];
#pragma unroll
            for (int cc = 0; cc < 10; ++cc) {
                unsigned long long m = __ballot(yv == cc);
                if ((tid & 63) == 0) loc[cc] += __popcll(m);
            }
        }
        if ((tid & 63) == 0)
#pragma unroll
            for (int cc = 0; cc < 10; ++cc) atomicAdd(&hist[cc], loc[cc]);
    }
    __syncthreads();

    const int I = r >> 7, Jc = r >> 8;
    float sa = 0.f, sb = 0.f;
    // Row-credit: blocks (I, J), J in [0, I>>1]. base(2a)=a^2+a, base(2a+1)=(a+1)^2.
    {
        const int a = I >> 1;
        const int base = (I & 1) ? (a + 1) * (a + 1) : a * a + a;
        const int lr = r & 127;
        for (int J = 0; J <= (I >> 1); ++J) {
            float2 p = rowPart[(size_t)(base + J) * 128 + lr];
            sa += p.x; sb += p.y;
        }
    }
    // Col-credit: blocks (Ip, Jc), Ip in [2*Jc, 63].
    {
        const int lc = r & 255;
        for (int Ip = 2 * Jc; Ip < 64; ++Ip) {
            const int ap = Ip >> 1;
            const int bb = ((Ip & 1) ? (ap + 1) * (ap + 1) : ap * ap + ap) + Jc;
            float2 p = colPart[(size_t)bb * 256 + lc];
            sa += p.x; sb += p.y;
        }
    }
    const int c = hist[y[r] & 15];
    const float M = __expf(0.5f * TINV);
    const float A = (n - c) > 0 ? sa : 1.0f;
    const float B = (c - 1) > 0 ? sb : 1.0f;
    float s = log1pf(M * A * B);
#pragma unroll
    for (int off = 32; off; off >>= 1) s += __shfl_xor(s, off, 64);
    if ((tid & 63) == 0) red[tid >> 6] = s;
    __syncthreads();
    if (tid == 0)
        atomicAdd(out, (red[0] + red[1] + red[2] + red[3]) / (float)n);
}

extern "C" void kernel_launch(void* const* d_in, const int* in_sizes, int n_in,
                              void* d_out, int out_size, void* d_ws, size_t ws_size,
                              hipStream_t stream) {
    const float* P = (const float*)d_in[0];
    const int* y   = (const int*)d_in[1];
    float* out     = (float*)d_out;
    const int n = in_sizes[1];  // 8192

    unsigned short* Pn = (unsigned short*)d_ws;
    float2* rowPart = (float2*)((char*)d_ws + (size_t)n * NF * 2);
    float2* colPart = rowPart + 1056 * 128;

    hipMemsetAsync(out, 0, sizeof(float), stream);
    k_prep<<<n / 4, 256, 0, stream>>>(P, Pn);
    k_main<<<1056, 256, 0, stream>>>(Pn, y, rowPart, colPart);
    k_final<<<n / 256, 256, 0, stream>>>(rowPart, colPart, y, out, n);
}

// Round 11
// 153.141 us; speedup vs baseline: 1.2327x; 1.2327x over previous
//
#include <hip/hip_runtime.h>
#include <hip/hip_bf16.h>

// n=8192 rows, d=256 feat, 10 classes.
// loss = mean_i log1p(exp(0.5/0.7) * A_i * B_i)
//   A_i = sum_{j: y_j!=y_i} exp(sim_ij/0.7), B_i = sum_{j!=i: y_j==y_i} exp(-sim_ij/0.7)
//   sim = rownorm(P) @ rownorm(P)^T
//
// R11 = R10 minus the last-block fusion (it was a flaky visibility race ->
// intermittent NaN; not provably sound, reverted). Kept, both validated in
// R10's correctness launch:
//  1. Grid 2048 (256-col groups): tail makespan 2T -> 1.5T on ~768 slots.
//  2. Diet epilogue: diag specialization + rT/rB trick (rA = rT - rB).
// k_final back as its own dispatch, parallel (32 blocks, R9-validated):
// ballot hist + per-row log1p + atomic merge into memset-zeroed out[0].
// Cross-kernel visibility of Aacc/Bacc is guaranteed at kernel boundaries.
// R7 invariants preserved: kc-major LDS (0 bank conflicts), zero staging
// VGPRs via global_load_lds, afr in registers, (256,3) -> no spills.

#define NF 256
#define TINV (1.0f / 0.7f)
#define SC2 2.0609929398439434f  // (1/0.7)*log2(e)

typedef __attribute__((ext_vector_type(8))) short short8;
typedef __attribute__((ext_vector_type(4))) float float4v;

typedef const __attribute__((address_space(1))) unsigned int glb_u32;
typedef __attribute__((address_space(3))) unsigned int lds_u32;

// One wave per row: normalize to bf16. Zeroes Aacc/Bacc.
__global__ __launch_bounds__(256)
void k_prep(const float* __restrict__ P, unsigned short* __restrict__ Pn,
            float* __restrict__ AB) {
    int wave = threadIdx.x >> 6, lane = threadIdx.x & 63;
    int row = blockIdx.x * 4 + wave;
    if (threadIdx.x < 8) AB[blockIdx.x * 8 + threadIdx.x] = 0.f;  // 2048*8 = 2n
    float4 v = *(const float4*)(P + (size_t)row * NF + lane * 4);
    float sq = v.x * v.x + v.y * v.y + v.z * v.z + v.w * v.w;
#pragma unroll
    for (int off = 32; off; off >>= 1) sq += __shfl_xor(sq, off, 64);
    float r = rsqrtf(sq);
    __hip_bfloat16 h0 = __float2bfloat16(v.x * r), h1 = __float2bfloat16(v.y * r),
                   h2 = __float2bfloat16(v.z * r), h3 = __float2bfloat16(v.w * r);
    ushort4 o = { *(unsigned short*)&h0, *(unsigned short*)&h1,
                  *(unsigned short*)&h2, *(unsigned short*)&h3 };
    *(ushort4*)(Pn + (size_t)row * NF + lane * 4) = o;
}

__global__ __launch_bounds__(256, 3)
void k_main(const unsigned short* __restrict__ Pn, const int* __restrict__ y,
            float* __restrict__ Aacc, float* __restrict__ Bacc) {
    __shared__ __align__(16) unsigned short Bs[64 * NF];  // one 64-col chunk
    __shared__ int yc[256];

    const int tid = threadIdx.x;
    const int I = blockIdx.x >> 5;        // 64 row panels of 128
    const int g = blockIdx.x & 31;        // 32 col groups of 256
    const int rb = I * 128, cb0 = g * 256;
    const bool diag = (g == (I >> 1));    // only these blocks can see i==j

    yc[tid] = y[cb0 + tid];

    const int lane = tid & 63, wave = tid >> 6;
    const int quad = lane >> 4, l15 = lane & 15;

    // A-frags: wave's 32 rows x full K=256. m=l15, k=quad*8+j (16x16x32).
    const unsigned short* pa = Pn + (size_t)(rb + wave * 32 + l15) * NF + quad * 8;
    short8 afr[2][8];
#pragma unroll
    for (int tr = 0; tr < 2; ++tr)
#pragma unroll
        for (int ks = 0; ks < 8; ++ks)
            afr[tr][ks] = *(const short8*)(pa + (size_t)tr * 16 * NF + ks * 32);

    // Row classes byte-packed (rows tr*16 + quad*4 + r).
    unsigned yis[2];
#pragma unroll
    for (int tr = 0; tr < 2; ++tr) {
        int4 v = *(const int4*)(y + rb + wave * 32 + tr * 16 + quad * 4);
        yis[tr] = (unsigned)(v.x & 255) | ((unsigned)(v.y & 255) << 8) |
                  ((unsigned)(v.z & 255) << 16) | ((unsigned)(v.w & 255) << 24);
    }

    float rT[2][4], rB[2][4];   // rT = all contributions, rB = same-class only
#pragma unroll
    for (int tr = 0; tr < 2; ++tr)
#pragma unroll
        for (int r = 0; r < 4; ++r) { rT[tr][r] = 0.f; rB[tr][r] = 0.f; }

    // DMA one 64-col chunk (kc-major: ushort addr = kc*512 + col*8).
    // Conflict-free both directions (R7-verified: SQ_LDS_BANK_CONFLICT=0).
#define DMA_CHUNK(c)                                                          \
    {                                                                         \
        _Pragma("unroll")                                                     \
        for (int i = 0; i < 8; ++i) {                                         \
            const int kc = wave * 8 + i;                                      \
            const unsigned short* src =                                       \
                Pn + (size_t)(cb0 + (c) * 64 + lane) * NF + kc * 8;           \
            __builtin_amdgcn_global_load_lds((glb_u32*)src,                   \
                (lds_u32*)&Bs[kc * 512], 16, 0, 0);                           \
        }                                                                     \
    }

    DMA_CHUNK(0)

#pragma unroll 1
    for (int c = 0; c < 4; ++c) {
        __syncthreads();   // barrier drains DMA vmcnt -> Bs ready

        float4v acc[2][4];
#pragma unroll
        for (int a = 0; a < 2; ++a)
#pragma unroll
            for (int b = 0; b < 4; ++b) acc[a][b] = (float4v){0.f, 0.f, 0.f, 0.f};

#pragma unroll
        for (int ks = 0; ks < 8; ++ks) {
            short8 fb[4];
#pragma unroll
            for (int tc = 0; tc < 4; ++tc)
                fb[tc] = *(const short8*)&Bs[(ks * 4 + quad) * 512 + (tc * 16 + l15) * 8];
#pragma unroll
            for (int tr = 0; tr < 2; ++tr)
#pragma unroll
                for (int tc = 0; tc < 4; ++tc)
                    acc[tr][tc] = __builtin_amdgcn_mfma_f32_16x16x32_bf16(
                        afr[tr][ks], fb[tc], acc[tr][tc], 0, 0, 0);
        }
        __syncthreads();   // all waves done reading Bs
        if (c < 3) DMA_CHUNK(c + 1)

        // Fused epilogue. C/D: col=l15, row=quad*4+reg.
        if (!diag) {
#pragma unroll
            for (int tc = 0; tc < 4; ++tc) {
                const int yj = yc[c * 64 + tc * 16 + l15];
#pragma unroll
                for (int tr = 0; tr < 2; ++tr)
#pragma unroll
                    for (int r = 0; r < 4; ++r) {
                        const float s = acc[tr][tc][r];
                        const bool same = (((yis[tr] >> (8 * r)) & 255) == (unsigned)yj);
                        const float e = exp2f(s * (same ? -SC2 : SC2));
                        rT[tr][r] += e;                    // unmasked total
                        rB[tr][r] += same ? e : 0.f;       // same-class part
                    }
            }
        } else {
#pragma unroll
            for (int tc = 0; tc < 4; ++tc) {
                const int jl = c * 64 + tc * 16 + l15;
                const int yj = yc[jl];
                const int gj = cb0 + jl;
#pragma unroll
                for (int tr = 0; tr < 2; ++tr) {
                    const int gi0 = rb + wave * 32 + tr * 16 + quad * 4;
#pragma unroll
                    for (int r = 0; r < 4; ++r) {
                        const float s = acc[tr][tc][r];
                        const bool same = (((yis[tr] >> (8 * r)) & 255) == (unsigned)yj);
                        const bool ne = (gi0 + r != gj);
                        const float e = exp2f(s * (same ? -SC2 : SC2));
                        rT[tr][r] += ne ? e : 0.f;
                        rB[tr][r] += (same && ne) ? e : 0.f;
                    }
                }
            }
        }
    }

    // Butterfly over the 16 col-lanes; quad leaders issue row atomics.
#pragma unroll
    for (int tr = 0; tr < 2; ++tr)
#pragma unroll
        for (int r = 0; r < 4; ++r) {
#pragma unroll
            for (int off = 1; off < 16; off <<= 1) {
                rT[tr][r] += __shfl_xor(rT[tr][r], off, 64);
                rB[tr][r] += __shfl_xor(rB[tr][r], off, 64);
            }
        }
    if (l15 == 0) {
#pragma unroll
        for (int tr = 0; tr < 2; ++tr)
#pragma unroll
            for (int r = 0; r < 4; ++r) {
                const int gi = rb + wave * 32 + tr * 16 + quad * 4 + r;
                atomicAdd(&Aacc[gi], rT[tr][r] - rB[tr][r]);  // diff-class
                atomicAdd(&Bacc[gi], rB[tr][r]);              // same-class
            }
    }
}

// 32 blocks x 256: ballot hist, per-row log1p, atomic merge into zeroed out.
__global__ __launch_bounds__(256)
void k_final(const float* __restrict__ Aacc, const float* __restrict__ Bacc,
             const int* __restrict__ y, float* __restrict__ out, int n) {
    __shared__ int hist[16];
    __shared__ float red[4];
    const int tid = threadIdx.x;
    const int i0 = blockIdx.x * 256 + tid;

    if (tid < 16) hist[tid] = 0;
    __syncthreads();
    {
        int loc[10];
#pragma unroll
        for (int cc = 0; cc < 10; ++cc) loc[cc] = 0;
        for (int i = tid; i < n; i += 256) {
            const int yv = y[i];
#pragma unroll
            for (int cc = 0; cc < 10; ++cc) {
                unsigned long long m = __ballot(yv == cc);
                if ((tid & 63) == 0) loc[cc] += __popcll(m);
            }
        }
        if ((tid & 63) == 0)
#pragma unroll
            for (int cc = 0; cc < 10; ++cc) atomicAdd(&hist[cc], loc[cc]);
    }
    __syncthreads();
    const float M = __expf(0.5f * TINV);
    const int cc = hist[y[i0] & 15];
    float a = Aacc[i0], b = Bacc[i0];
    a = (n - cc) > 0 ? a : 1.0f;
    b = (cc - 1) > 0 ? b : 1.0f;
    float s = log1pf(M * a * b);
#pragma unroll
    for (int off = 32; off; off >>= 1) s += __shfl_xor(s, off, 64);
    if ((tid & 63) == 0) red[tid >> 6] = s;
    __syncthreads();
    if (tid == 0)
        atomicAdd(out, (red[0] + red[1] + red[2] + red[3]) / (float)n);
}

extern "C" void kernel_launch(void* const* d_in, const int* in_sizes, int n_in,
                              void* d_out, int out_size, void* d_ws, size_t ws_size,
                              hipStream_t stream) {
    const float* P = (const float*)d_in[0];
    const int* y   = (const int*)d_in[1];
    float* out     = (float*)d_out;
    const int n = in_sizes[1];  // 8192

    // ws: Pn bf16 [n*256] | Aacc f32 [n] | Bacc f32 [n]
    unsigned short* Pn = (unsigned short*)d_ws;
    float* Aacc = (float*)((char*)d_ws + (size_t)n * NF * 2);
    float* Bacc = Aacc + n;

    hipMemsetAsync(out, 0, sizeof(float), stream);
    k_prep<<<n / 4, 256, 0, stream>>>(P, Pn, Aacc);
    k_main<<<(n / 128) * (n / 256), 256, 0, stream>>>(Pn, y, Aacc, Bacc);
    k_final<<<n / 256, 256, 0, stream>>>(Aacc, Bacc, y, out, n);
}